// Round 3
// baseline (141.705 us; speedup 1.0000x reference)
//
#include <hip/hip_runtime.h>

// ---------------------------------------------------------------------------
// Algebraic collapse of the whole model:
//   X[b, s, p]  = x[b, 0, ti*64+pr, tk*64+pc],  s = 8*ti+tk, p = 64*pr+pc
//   scores[b,h,i,j] ~ A'_h * G[b,i,j] + Bk'_h * sX[b,j]   (+ j-const terms
//                     that cancel in softmax);  G = token Gram of raw X
//   out[b,i,p] = sum_j W[b,i,j] * X[b,j,p] + const0,
//   W[b,i,j]   = sum_h g_h * softmax_j(scores)_h
//
// R2 lesson: the 8-block k2 reading 8.4 MB of partials was latency-bound
// (46 us @ 98 GB/s). R3: k1 accumulates 4 pr-tiles in registers ->
// 128 partials (2 MB) instead of 512 (8.4 MB); k2's reduce is 16x smaller.
// ---------------------------------------------------------------------------

#define CONST_OFF 0                       // 16 floats: c0 at [12]
#define SXP_OFF   16                      // 128*64 partial token sums
#define WT_OFF    (16 + 128*64)           // W transposed: [b][j][i], 8*4096
#define PART_OFF  (WT_OFF + 8*4096)       // partial Grams: [128 blocks][4096]

// ---------------------------------------------------------------------------
// K1: per-(b, prg) partial Gram; each block accumulates 4 pr-tiles in
// registers. 128 blocks x 256 threads. LDS tile xs[64 tokens][68] (pad 68
// keeps float4 reads at <=2-way bank aliasing = free per m136).
// ---------------------------------------------------------------------------
__global__ __launch_bounds__(256) void k1_gram(const float* __restrict__ x,
                                               float* __restrict__ ws)
{
    __shared__ float xs[64 * 68];
    int b = blockIdx.x >> 4, prg = blockIdx.x & 15;
    int t = threadIdx.x;
    const float* xb = x + (size_t)b * 262144;
    int tix = t & 15, tjx = t >> 4;

    float acc[4][4];
    #pragma unroll
    for (int u = 0; u < 4; ++u)
        #pragma unroll
        for (int v = 0; v < 4; ++v) acc[u][v] = 0.f;
    float tsum = 0.f;

    for (int it = 0; it < 4; ++it) {
        int pr = prg * 4 + it;
        __syncthreads();                  // xs safe to overwrite
        #pragma unroll
        for (int k = 0; k < 4; ++k) {
            int q = t + 256 * k;          // float4 index within 8x512 row group
            int tj = q >> 7, col4 = q & 127;
            float4 v = *(const float4*)(xb + (tj * 64 + pr) * 512 + col4 * 4);
            int token = tj * 8 + (col4 >> 4);
            *(float4*)(&xs[token * 68 + (col4 & 15) * 4]) = v;
        }
        __syncthreads();

        #pragma unroll 4
        for (int cq = 0; cq < 16; ++cq) {
            float4 a[4], bb[4];
            #pragma unroll
            for (int u = 0; u < 4; ++u)
                a[u] = *(const float4*)(&xs[(tix + 16 * u) * 68 + 4 * cq]);
            #pragma unroll
            for (int v = 0; v < 4; ++v)
                bb[v] = *(const float4*)(&xs[(tjx + 16 * v) * 68 + 4 * cq]);
            #pragma unroll
            for (int u = 0; u < 4; ++u)
                #pragma unroll
                for (int v = 0; v < 4; ++v)
                    acc[u][v] += a[u].x * bb[v].x + a[u].y * bb[v].y +
                                 a[u].z * bb[v].z + a[u].w * bb[v].w;
        }
        if (t < 64) {                     // token-sum contribution of this pr
            float s = 0.f;
            for (int c = 0; c < 64; ++c) s += xs[t * 68 + c];
            tsum += s;
        }
    }

    float* part = ws + PART_OFF + (size_t)blockIdx.x * 4096;
    #pragma unroll
    for (int u = 0; u < 4; ++u)
        #pragma unroll
        for (int v = 0; v < 4; ++v)
            part[(tix + 16 * u) * 64 + (tjx + 16 * v)] = acc[u][v];

    if (t < 64) ws[SXP_OFF + blockIdx.x * 64 + t] = tsum;
}

// ---------------------------------------------------------------------------
// K2: per batch (8 blocks x 1024 threads):
//   phase 0: contract weights -> 13 scalars (redundant per block, trivial)
//   phase 1: reduce 16 partial Grams -> G (LDS), reduce partial token sums
//   phase 2: softmax over 4 heads, accumulate W
//   phase 3: write W^T[b][j][i]; block 0 publishes const0 for K3
// ---------------------------------------------------------------------------
__global__ __launch_bounds__(1024) void k2_attn(
    const float* __restrict__ w1, const float* __restrict__ b1,
    const float* __restrict__ wqkv, const float* __restrict__ wproj,
    const float* __restrict__ bproj, const float* __restrict__ w2,
    const float* __restrict__ b2, float* __restrict__ ws)
{
    __shared__ float arow[96], crow[96], pvec[32];
    __shared__ float cst[16];
    __shared__ float G_s[64 * 65];
    __shared__ float Wacc[64 * 65];
    __shared__ float sxp_s[16][64];
    __shared__ float sx_s[64];
    int b = blockIdx.x, t = threadIdx.x;

    // phase 0a: per-output-row contractions of wqkv with w1/b1, w2.wproj
    if (t < 96) {
        float sa = 0.f, sc = 0.f;
        for (int c = 0; c < 32; ++c) {
            float w = wqkv[t * 32 + c];
            sa += w * w1[c];
            sc += w * b1[c];
        }
        arow[t] = sa; crow[t] = sc;
    } else if (t < 128) {
        int c = t - 96;
        float s = 0.f;
        for (int oc = 0; oc < 32; ++oc) s += w2[oc] * wproj[oc * 32 + c];
        pvec[c] = s;
    }

    // phase 1a: reduce 16 partial Grams (coalesced, 4 acc chains)
    {
        const float* p0 = ws + PART_OFF + (size_t)(b * 16) * 4096 + t;
        float a0 = 0.f, a1 = 0.f, a2 = 0.f, a3 = 0.f;
        #pragma unroll
        for (int r = 0; r < 16; ++r) {
            const float* pr = p0 + (size_t)r * 4096;
            a0 += pr[0]; a1 += pr[1024]; a2 += pr[2048]; a3 += pr[3072];
        }
        int e0 = t;
        G_s[(e0 >> 6) * 65 + (e0 & 63)] = a0;  Wacc[(e0 >> 6) * 65 + (e0 & 63)] = 0.f;
        int e1 = t + 1024;
        G_s[(e1 >> 6) * 65 + (e1 & 63)] = a1;  Wacc[(e1 >> 6) * 65 + (e1 & 63)] = 0.f;
        int e2 = t + 2048;
        G_s[(e2 >> 6) * 65 + (e2 & 63)] = a2;  Wacc[(e2 >> 6) * 65 + (e2 & 63)] = 0.f;
        int e3 = t + 3072;
        G_s[(e3 >> 6) * 65 + (e3 & 63)] = a3;  Wacc[(e3 >> 6) * 65 + (e3 & 63)] = 0.f;
    }

    // phase 1b: reduce partial token sums (16 x 64 -> 64)
    {
        int j = t & 63, rg = t >> 6;     // rg in [0,16)
        sxp_s[rg][j] = ws[SXP_OFF + (b * 16 + rg) * 64 + j];
    }
    __syncthreads();
    if (t < 64) {
        float s = 0.f;
        #pragma unroll
        for (int r = 0; r < 16; ++r) s += sxp_s[r][t];
        sx_s[t] = s;
    }

    // phase 0b: combine into the 13 scalars
    const float scale = 1.0f / (4096.0f * 2.8284271247461903f); // 1/(P*sqrt(d))
    if (t >= 64 && t < 68) {
        int h = t - 64;
        float A = 0.f, Bk = 0.f, g = 0.f;
        #pragma unroll
        for (int dd = 0; dd < 8; ++dd) {
            int o = h * 8 + dd;
            A  += arow[o] * arow[32 + o];   // aq . ak
            Bk += crow[o] * arow[32 + o];   // cq . ak
            g  += pvec[o] * arow[64 + o];   // pvec . av
        }
        cst[h]     = A * scale;
        cst[4 + h] = Bk * scale;
        cst[8 + h] = g;
    } else if (t == 68) {
        float c0 = b2[0];
        for (int c = 0; c < 32; ++c)  c0 += pvec[c] * crow[64 + c];
        for (int oc = 0; oc < 32; ++oc) c0 += w2[oc] * bproj[oc];
        cst[12] = c0;
    }
    __syncthreads();

    // phase 2: softmax per (head, row) and accumulate W
    if (t < 256) {
        int h = t >> 6, i = t & 63;
        float A  = cst[h];
        float Bk = cst[4 + h];
        float g  = cst[8 + h];
        float p[64];
        float m = -1e30f;
        #pragma unroll
        for (int j = 0; j < 64; ++j) {
            float s = A * G_s[i * 65 + j] + Bk * sx_s[j];
            p[j] = s;
            m = fmaxf(m, s);
        }
        float Z = 0.f;
        #pragma unroll
        for (int j = 0; j < 64; ++j) {
            float e = __expf(p[j] - m);
            p[j] = e;
            Z += e;
        }
        float coef = g / Z;
        #pragma unroll
        for (int j = 0; j < 64; ++j)
            atomicAdd(&Wacc[i * 65 + j], coef * p[j]);
    }
    __syncthreads();

    // phase 3: write W^T (coalesced on global; LDS read is bank-distinct)
    #pragma unroll
    for (int k = 0; k < 4; ++k) {
        int g_ = t + 1024 * k;           // global flat index j*64+i
        int i = g_ & 63, j = g_ >> 6;
        ws[WT_OFF + b * 4096 + g_] = Wacc[i * 65 + j];
    }
    if (b == 0 && t == 0) ws[CONST_OFF + 12] = cst[12];
}

// ---------------------------------------------------------------------------
// K3: out[b, ti*64+pr, tk*64+c] = const0 + sum_j W[b, 8ti+tk, j] * X_j(pr,c)
// 512 blocks x 256 threads; same LDS tiling as K1 plus staged W^T.
// ---------------------------------------------------------------------------
__global__ __launch_bounds__(256) void k3_apply(const float* __restrict__ x,
                                                const float* __restrict__ ws,
                                                float* __restrict__ out)
{
    __shared__ float xs[64 * 68];
    __shared__ float Wt_s[64 * 68];
    int b = blockIdx.x >> 6, pr = blockIdx.x & 63;
    int t = threadIdx.x;
    const float* xb = x + (size_t)b * 262144;
    #pragma unroll
    for (int k = 0; k < 4; ++k) {
        int q = t + 256 * k;
        int tj = q >> 7, col4 = q & 127;
        float4 v = *(const float4*)(xb + (tj * 64 + pr) * 512 + col4 * 4);
        int token = tj * 8 + (col4 >> 4);
        *(float4*)(&xs[token * 68 + (col4 & 15) * 4]) = v;
        // stage W^T: ws[WT_OFF + b*4096 + j*64 + i] -> Wt_s[j][i]
        int j = q >> 4, i0 = (q & 15) * 4;
        float4 wv = *(const float4*)(ws + WT_OFF + b * 4096 + q * 4);
        *(float4*)(&Wt_s[j * 68 + i0]) = wv;
    }
    __syncthreads();

    int tcx = t & 15, tiy = t >> 4;
    float acc[4][4];                       // [u = i offset][v = c offset]
    #pragma unroll
    for (int u = 0; u < 4; ++u)
        #pragma unroll
        for (int v = 0; v < 4; ++v) acc[u][v] = 0.f;

    #pragma unroll 8
    for (int j = 0; j < 64; ++j) {
        float4 wv = *(const float4*)(&Wt_s[j * 68 + 4 * tiy]); // 4 rows i
        float4 xv = *(const float4*)(&xs[j * 68 + 4 * tcx]);   // 4 cols c
        acc[0][0] += wv.x * xv.x; acc[0][1] += wv.x * xv.y;
        acc[0][2] += wv.x * xv.z; acc[0][3] += wv.x * xv.w;
        acc[1][0] += wv.y * xv.x; acc[1][1] += wv.y * xv.y;
        acc[1][2] += wv.y * xv.z; acc[1][3] += wv.y * xv.w;
        acc[2][0] += wv.z * xv.x; acc[2][1] += wv.z * xv.y;
        acc[2][2] += wv.z * xv.z; acc[2][3] += wv.z * xv.w;
        acc[3][0] += wv.w * xv.x; acc[3][1] += wv.w * xv.y;
        acc[3][2] += wv.w * xv.z; acc[3][3] += wv.w * xv.w;
    }

    float c0 = ws[CONST_OFF + 12];
    float* ob = out + (size_t)b * 262144;
    #pragma unroll
    for (int u = 0; u < 4; ++u) {
        int i = 4 * tiy + u;
        int ti = i >> 3, tk = i & 7;
        float4 r;
        r.x = acc[u][0] + c0; r.y = acc[u][1] + c0;
        r.z = acc[u][2] + c0; r.w = acc[u][3] + c0;
        *(float4*)(ob + (ti * 64 + pr) * 512 + tk * 64 + 4 * tcx) = r;
    }
}

extern "C" void kernel_launch(void* const* d_in, const int* in_sizes, int n_in,
                              void* d_out, int out_size, void* d_ws, size_t ws_size,
                              hipStream_t stream) {
    const float* x     = (const float*)d_in[0];
    // d_in[1] = n, d_in[2] = m  (fixed 8 by setup_inputs)
    const float* w1    = (const float*)d_in[3];
    const float* b1    = (const float*)d_in[4];
    const float* wqkv  = (const float*)d_in[5];
    const float* wproj = (const float*)d_in[6];
    const float* bproj = (const float*)d_in[7];
    const float* w2    = (const float*)d_in[8];
    const float* b2    = (const float*)d_in[9];
    float* out = (float*)d_out;
    float* ws  = (float*)d_ws;

    k1_gram<<<128, 256, 0, stream>>>(x, ws);
    k2_attn<<<8, 1024, 0, stream>>>(w1, b1, wqkv, wproj, bproj, w2, b2, ws);
    k3_apply<<<512, 256, 0, stream>>>(x, ws, out);
}

// Round 4
// 107.032 us; speedup vs baseline: 1.3240x; 1.3240x over previous
//
#include <hip/hip_runtime.h>

// ---------------------------------------------------------------------------
// Algebraic collapse of the whole model:
//   X[b, s, p]  = x[b, 0, ti*64+pr, tk*64+pc],  s = 8*ti+tk, p = 64*pr+pc
//   scores[b,h,i,j] ~ A'_h * G[b,i,j] + Bk'_h * sX[b,j]   (+ j-const terms
//                     that cancel in softmax);  G = token Gram of raw X
//   out[b,i,p] = sum_j W[b,i,j] * X[b,j,p] + const0,
//   W[b,i,j]   = sum_h g_h * softmax_j(scores)_h
//
// R3 lesson: k2's 44 us was a VGPR spill (p[64] array, VGPR_Count=40 ->
// scratch round-trips at 1% occupancy), NOT memory traffic. R4: recompute
// scores from LDS (1 FMA each), no register array, no LDS atomics.
// ---------------------------------------------------------------------------

#define CONST_OFF 0                       // 16 floats: c0 at [12]
#define SXP_OFF   16                      // 128*64 partial token sums
#define WT_OFF    (16 + 128*64)           // W transposed: [b][j][i], 8*4096
#define PART_OFF  (WT_OFF + 8*4096)       // partial Grams: [128 blocks][4096]

// ---------------------------------------------------------------------------
// K1: per-(b, prg) partial Gram; each block accumulates 4 pr-tiles in
// registers. 128 blocks x 256 threads. LDS tile xs[64 tokens][68] (pad 68
// keeps float4 reads at <=2-way bank aliasing = free per m136).
// ---------------------------------------------------------------------------
__global__ __launch_bounds__(256) void k1_gram(const float* __restrict__ x,
                                               float* __restrict__ ws)
{
    __shared__ float xs[64 * 68];
    int b = blockIdx.x >> 4, prg = blockIdx.x & 15;
    int t = threadIdx.x;
    const float* xb = x + (size_t)b * 262144;
    int tix = t & 15, tjx = t >> 4;

    float acc[4][4];
    #pragma unroll
    for (int u = 0; u < 4; ++u)
        #pragma unroll
        for (int v = 0; v < 4; ++v) acc[u][v] = 0.f;
    float tsum = 0.f;

    for (int it = 0; it < 4; ++it) {
        int pr = prg * 4 + it;
        __syncthreads();                  // xs safe to overwrite
        #pragma unroll
        for (int k = 0; k < 4; ++k) {
            int q = t + 256 * k;          // float4 index within 8x512 row group
            int tj = q >> 7, col4 = q & 127;
            float4 v = *(const float4*)(xb + (tj * 64 + pr) * 512 + col4 * 4);
            int token = tj * 8 + (col4 >> 4);
            *(float4*)(&xs[token * 68 + (col4 & 15) * 4]) = v;
        }
        __syncthreads();

        #pragma unroll 4
        for (int cq = 0; cq < 16; ++cq) {
            float4 a[4], bb[4];
            #pragma unroll
            for (int u = 0; u < 4; ++u)
                a[u] = *(const float4*)(&xs[(tix + 16 * u) * 68 + 4 * cq]);
            #pragma unroll
            for (int v = 0; v < 4; ++v)
                bb[v] = *(const float4*)(&xs[(tjx + 16 * v) * 68 + 4 * cq]);
            #pragma unroll
            for (int u = 0; u < 4; ++u)
                #pragma unroll
                for (int v = 0; v < 4; ++v)
                    acc[u][v] += a[u].x * bb[v].x + a[u].y * bb[v].y +
                                 a[u].z * bb[v].z + a[u].w * bb[v].w;
        }
        if (t < 64) {                     // token-sum contribution of this pr
            float s = 0.f;
            for (int c = 0; c < 64; ++c) s += xs[t * 68 + c];
            tsum += s;
        }
    }

    float* part = ws + PART_OFF + (size_t)blockIdx.x * 4096;
    #pragma unroll
    for (int u = 0; u < 4; ++u)
        #pragma unroll
        for (int v = 0; v < 4; ++v)
            part[(tix + 16 * u) * 64 + (tjx + 16 * v)] = acc[u][v];

    if (t < 64) ws[SXP_OFF + blockIdx.x * 64 + t] = tsum;
}

// ---------------------------------------------------------------------------
// K2: per batch (8 blocks x 1024 threads):
//   phase 0: contract weights -> 13 scalars (redundant per block, trivial)
//   phase 1: reduce 16 partial Grams -> G_s (LDS), reduce token sums
//   phase 2a: per (head,row): m and Z via LDS recompute -> coef_s, m_s
//   phase 2b: all 1024 threads: W^T[j][i] = sum_h coef*exp(s-m) -> global
// No register score array (R3's spill), no LDS atomics.
// ---------------------------------------------------------------------------
__global__ __launch_bounds__(1024) void k2_attn(
    const float* __restrict__ w1, const float* __restrict__ b1,
    const float* __restrict__ wqkv, const float* __restrict__ wproj,
    const float* __restrict__ bproj, const float* __restrict__ w2,
    const float* __restrict__ b2, float* __restrict__ ws)
{
    __shared__ float arow[96], crow[96], pvec[32];
    __shared__ float cst[16];
    __shared__ float G_s[64 * 65];
    __shared__ float sxp_s[16][64];
    __shared__ float sx_s[64];
    __shared__ float coef_s[4][64];
    __shared__ float m_s[4][64];
    int b = blockIdx.x, t = threadIdx.x;

    // phase 0a: per-output-row contractions of wqkv with w1/b1, w2.wproj
    if (t < 96) {
        float sa = 0.f, sc = 0.f;
        for (int c = 0; c < 32; ++c) {
            float w = wqkv[t * 32 + c];
            sa += w * w1[c];
            sc += w * b1[c];
        }
        arow[t] = sa; crow[t] = sc;
    } else if (t < 128) {
        int c = t - 96;
        float s = 0.f;
        for (int oc = 0; oc < 32; ++oc) s += w2[oc] * wproj[oc * 32 + c];
        pvec[c] = s;
    }

    // phase 1a: reduce 16 partial Grams (coalesced, 4 acc chains)
    {
        const float* p0 = ws + PART_OFF + (size_t)(b * 16) * 4096 + t;
        float a0 = 0.f, a1 = 0.f, a2 = 0.f, a3 = 0.f;
        #pragma unroll
        for (int r = 0; r < 16; ++r) {
            const float* pr = p0 + (size_t)r * 4096;
            a0 += pr[0]; a1 += pr[1024]; a2 += pr[2048]; a3 += pr[3072];
        }
        int e0 = t;
        G_s[(e0 >> 6) * 65 + (e0 & 63)] = a0;
        int e1 = t + 1024;
        G_s[(e1 >> 6) * 65 + (e1 & 63)] = a1;
        int e2 = t + 2048;
        G_s[(e2 >> 6) * 65 + (e2 & 63)] = a2;
        int e3 = t + 3072;
        G_s[(e3 >> 6) * 65 + (e3 & 63)] = a3;
    }

    // phase 1b: reduce partial token sums (16 x 64 -> 64)
    {
        int j = t & 63, rg = t >> 6;     // rg in [0,16)
        sxp_s[rg][j] = ws[SXP_OFF + (b * 16 + rg) * 64 + j];
    }
    __syncthreads();
    if (t < 64) {
        float s = 0.f;
        #pragma unroll
        for (int r = 0; r < 16; ++r) s += sxp_s[r][t];
        sx_s[t] = s;
    }

    // phase 0b: combine into the 13 scalars
    const float scale = 1.0f / (4096.0f * 2.8284271247461903f); // 1/(P*sqrt(d))
    if (t >= 64 && t < 68) {
        int h = t - 64;
        float A = 0.f, Bk = 0.f, g = 0.f;
        #pragma unroll
        for (int dd = 0; dd < 8; ++dd) {
            int o = h * 8 + dd;
            A  += arow[o] * arow[32 + o];   // aq . ak
            Bk += crow[o] * arow[32 + o];   // cq . ak
            g  += pvec[o] * arow[64 + o];   // pvec . av
        }
        cst[h]     = A * scale;
        cst[4 + h] = Bk * scale;
        cst[8 + h] = g;
    } else if (t == 68) {
        float c0 = b2[0];
        for (int c = 0; c < 32; ++c)  c0 += pvec[c] * crow[64 + c];
        for (int oc = 0; oc < 32; ++oc) c0 += w2[oc] * bproj[oc];
        cst[12] = c0;
    }
    __syncthreads();

    // phase 2a: per (head, row): running max and Z, recomputing s from LDS
    if (t < 256) {
        int h = t >> 6, i = t & 63;
        float A  = cst[h];
        float Bk = cst[4 + h];
        float g  = cst[8 + h];
        float m = -1e30f;
        for (int j = 0; j < 64; ++j) {
            float s = A * G_s[i * 65 + j] + Bk * sx_s[j];
            m = fmaxf(m, s);
        }
        float Z = 0.f;
        for (int j = 0; j < 64; ++j) {
            float s = A * G_s[i * 65 + j] + Bk * sx_s[j];
            Z += __expf(s - m);
        }
        coef_s[h][i] = g / Z;
        m_s[h][i]    = m;
    }
    __syncthreads();

    // phase 2b: every thread writes 4 entries of W^T (coalesced on global)
    {
        float A0 = cst[0], A1 = cst[1], A2 = cst[2], A3 = cst[3];
        float B0 = cst[4], B1 = cst[5], B2 = cst[6], B3 = cst[7];
        #pragma unroll
        for (int k = 0; k < 4; ++k) {
            int e = t + 1024 * k;         // flat index j*64+i
            int j = e >> 6, i = e & 63;
            float G  = G_s[i * 65 + j];
            float sx = sx_s[j];
            float w =
                coef_s[0][i] * __expf(A0 * G + B0 * sx - m_s[0][i]) +
                coef_s[1][i] * __expf(A1 * G + B1 * sx - m_s[1][i]) +
                coef_s[2][i] * __expf(A2 * G + B2 * sx - m_s[2][i]) +
                coef_s[3][i] * __expf(A3 * G + B3 * sx - m_s[3][i]);
            ws[WT_OFF + b * 4096 + e] = w;
        }
    }
    if (b == 0 && t == 0) ws[CONST_OFF + 12] = cst[12];
}

// ---------------------------------------------------------------------------
// K3: out[b, ti*64+pr, tk*64+c] = const0 + sum_j W[b, 8ti+tk, j] * X_j(pr,c)
// 512 blocks x 256 threads; same LDS tiling as K1 plus staged W^T.
// ---------------------------------------------------------------------------
__global__ __launch_bounds__(256) void k3_apply(const float* __restrict__ x,
                                                const float* __restrict__ ws,
                                                float* __restrict__ out)
{
    __shared__ float xs[64 * 68];
    __shared__ float Wt_s[64 * 68];
    int b = blockIdx.x >> 6, pr = blockIdx.x & 63;
    int t = threadIdx.x;
    const float* xb = x + (size_t)b * 262144;
    #pragma unroll
    for (int k = 0; k < 4; ++k) {
        int q = t + 256 * k;
        int tj = q >> 7, col4 = q & 127;
        float4 v = *(const float4*)(xb + (tj * 64 + pr) * 512 + col4 * 4);
        int token = tj * 8 + (col4 >> 4);
        *(float4*)(&xs[token * 68 + (col4 & 15) * 4]) = v;
        // stage W^T: ws[WT_OFF + b*4096 + j*64 + i] -> Wt_s[j][i]
        int j = q >> 4, i0 = (q & 15) * 4;
        float4 wv = *(const float4*)(ws + WT_OFF + b * 4096 + q * 4);
        *(float4*)(&Wt_s[j * 68 + i0]) = wv;
    }
    __syncthreads();

    int tcx = t & 15, tiy = t >> 4;
    float acc[4][4];                       // [u = i offset][v = c offset]
    #pragma unroll
    for (int u = 0; u < 4; ++u)
        #pragma unroll
        for (int v = 0; v < 4; ++v) acc[u][v] = 0.f;

    #pragma unroll 8
    for (int j = 0; j < 64; ++j) {
        float4 wv = *(const float4*)(&Wt_s[j * 68 + 4 * tiy]); // 4 rows i
        float4 xv = *(const float4*)(&xs[j * 68 + 4 * tcx]);   // 4 cols c
        acc[0][0] += wv.x * xv.x; acc[0][1] += wv.x * xv.y;
        acc[0][2] += wv.x * xv.z; acc[0][3] += wv.x * xv.w;
        acc[1][0] += wv.y * xv.x; acc[1][1] += wv.y * xv.y;
        acc[1][2] += wv.y * xv.z; acc[1][3] += wv.y * xv.w;
        acc[2][0] += wv.z * xv.x; acc[2][1] += wv.z * xv.y;
        acc[2][2] += wv.z * xv.z; acc[2][3] += wv.z * xv.w;
        acc[3][0] += wv.w * xv.x; acc[3][1] += wv.w * xv.y;
        acc[3][2] += wv.w * xv.z; acc[3][3] += wv.w * xv.w;
    }

    float c0 = ws[CONST_OFF + 12];
    float* ob = out + (size_t)b * 262144;
    #pragma unroll
    for (int u = 0; u < 4; ++u) {
        int i = 4 * tiy + u;
        int ti = i >> 3, tk = i & 7;
        float4 r;
        r.x = acc[u][0] + c0; r.y = acc[u][1] + c0;
        r.z = acc[u][2] + c0; r.w = acc[u][3] + c0;
        *(float4*)(ob + (ti * 64 + pr) * 512 + tk * 64 + 4 * tcx) = r;
    }
}

extern "C" void kernel_launch(void* const* d_in, const int* in_sizes, int n_in,
                              void* d_out, int out_size, void* d_ws, size_t ws_size,
                              hipStream_t stream) {
    const float* x     = (const float*)d_in[0];
    // d_in[1] = n, d_in[2] = m  (fixed 8 by setup_inputs)
    const float* w1    = (const float*)d_in[3];
    const float* b1    = (const float*)d_in[4];
    const float* wqkv  = (const float*)d_in[5];
    const float* wproj = (const float*)d_in[6];
    const float* bproj = (const float*)d_in[7];
    const float* w2    = (const float*)d_in[8];
    const float* b2    = (const float*)d_in[9];
    float* out = (float*)d_out;
    float* ws  = (float*)d_ws;

    k1_gram<<<128, 256, 0, stream>>>(x, ws);
    k2_attn<<<8, 1024, 0, stream>>>(w1, b1, wqkv, wproj, bproj, w2, b2, ws);
    k3_apply<<<512, 256, 0, stream>>>(x, ws, out);
}

// Round 5
// 94.336 us; speedup vs baseline: 1.5021x; 1.1346x over previous
//
#include <hip/hip_runtime.h>

// ---------------------------------------------------------------------------
// Algebraic collapse of the whole model:
//   X[b, s, p]  = x[b, 0, ti*64+pr, tk*64+pc],  s = 8*ti+tk, p = 64*pr+pc
//   scores[b,h,i,j] ~ A'_h * G[b,i,j] + Bk'_h * sX[b,j]   (+ j-const terms
//                     that cancel in softmax);  G = token Gram of raw X
//   out[b,i,p] = sum_j W[b,i,j] * X[b,j,p] + const0,
//   W[b,i,j]   = sum_h g_h * softmax_j(scores)_h
//
// R4 lesson: k2 fixed (spill removed). k1 (~10 us) was LDS-issue bound at
// 2 FMA/float. R5: k1 Gram via bf16 MFMA (A'~8e-7 makes bf16 G-error ~4e-7
// in scores -> negligible). k2/k3 unchanged.
// ---------------------------------------------------------------------------

#define CONST_OFF 0                       // 16 floats: c0 at [12]
#define SXP_OFF   16                      // 128*64 partial token sums
#define WT_OFF    (16 + 128*64)           // W transposed: [b][j][i], 8*4096
#define PART_OFF  (WT_OFF + 8*4096)       // partial Grams: [128 blocks][4096]

typedef __attribute__((ext_vector_type(8))) short bf16x8;
typedef __attribute__((ext_vector_type(4))) float f32x4;

__device__ __forceinline__ unsigned short f2bf(float f) {
    unsigned int u = __float_as_uint(f);
    u = (u + 0x7FFFu + ((u >> 16) & 1u)) >> 16;   // RNE
    return (unsigned short)u;
}

// ---------------------------------------------------------------------------
// K1: partial Gram via MFMA. 128 blocks (8 b x 16 prg) x 256 threads.
// Each block: K-chunk = 4 pr slices x 64 pc = 256. Stage x as bf16 into
// xsb[token][k], row stride 272 bf16 (544 B = 136 banks -> frag reads are
// 2-way aliased = free per m136). 4 waves x 4 j-tiles x 8 K-steps of
// mfma_f32_16x16x32_bf16. Token sums from bf16 LDS (err ~2e-7, negligible).
// ---------------------------------------------------------------------------
__global__ __launch_bounds__(256) void k1_gram(const float* __restrict__ x,
                                               float* __restrict__ ws)
{
    __shared__ unsigned short xsb[64 * 272];
    int b = blockIdx.x >> 4, prg = blockIdx.x & 15;
    int t = threadIdx.x;
    const float* xb = x + (size_t)b * 262144;

    #pragma unroll
    for (int prl = 0; prl < 4; ++prl) {
        int pr = prg * 4 + prl;
        #pragma unroll
        for (int k = 0; k < 4; ++k) {
            int q = t + 256 * k;          // float4 index within 8x512 rows
            int tj = q >> 7, col4 = q & 127;
            float4 v = *(const float4*)(xb + (tj * 64 + pr) * 512 + col4 * 4);
            int token = tj * 8 + (col4 >> 4);
            ushort4 h;
            h.x = f2bf(v.x); h.y = f2bf(v.y); h.z = f2bf(v.z); h.w = f2bf(v.w);
            *(ushort4*)(&xsb[token * 272 + prl * 64 + (col4 & 15) * 4]) = h;
        }
    }
    __syncthreads();

    // token-sum contribution of this K-chunk (from bf16 values; error ~1e-7)
    if (t < 64) {
        const uint4* p = (const uint4*)(&xsb[t * 272]);
        float s = 0.f;
        #pragma unroll
        for (int c = 0; c < 32; ++c) {    // 32 x 8 bf16 = 256 values
            uint4 u = p[c];
            s += __uint_as_float(u.x << 16) + __uint_as_float(u.x & 0xFFFF0000u)
               + __uint_as_float(u.y << 16) + __uint_as_float(u.y & 0xFFFF0000u)
               + __uint_as_float(u.z << 16) + __uint_as_float(u.z & 0xFFFF0000u)
               + __uint_as_float(u.w << 16) + __uint_as_float(u.w & 0xFFFF0000u);
        }
        ws[SXP_OFF + blockIdx.x * 64 + t] = s;
    }

    // MFMA: wave w owns i-tile iq=w; loops j-tiles. A and B frags both load
    // X[token = tile*16 + (lane&15)][k = s*32 + (lane>>4)*8 .. +7].
    int w = t >> 6, lane = t & 63;
    int m = lane & 15, quad = lane >> 4;
    f32x4 acc[4];
    #pragma unroll
    for (int jq = 0; jq < 4; ++jq) acc[jq] = (f32x4){0.f, 0.f, 0.f, 0.f};

    #pragma unroll
    for (int s = 0; s < 8; ++s) {
        int kb = s * 32 + quad * 8;
        bf16x8 a = *(const bf16x8*)(&xsb[(w * 16 + m) * 272 + kb]);
        #pragma unroll
        for (int jq = 0; jq < 4; ++jq) {
            bf16x8 bb = *(const bf16x8*)(&xsb[(jq * 16 + m) * 272 + kb]);
            acc[jq] = __builtin_amdgcn_mfma_f32_16x16x32_bf16(a, bb, acc[jq],
                                                              0, 0, 0);
        }
    }

    // C/D layout (m89): col = lane&15 (j), row = (lane>>4)*4 + reg (i)
    float* part = ws + PART_OFF + (size_t)blockIdx.x * 4096;
    #pragma unroll
    for (int jq = 0; jq < 4; ++jq)
        #pragma unroll
        for (int r = 0; r < 4; ++r)
            part[(w * 16 + quad * 4 + r) * 64 + jq * 16 + m] = acc[jq][r];
}

// ---------------------------------------------------------------------------
// K2: per batch (8 blocks x 1024 threads):
//   phase 0: contract weights -> 13 scalars (redundant per block, trivial)
//   phase 1: reduce 16 partial Grams -> G_s (LDS), reduce token sums
//   phase 2a: per (head,row): m and Z via LDS recompute -> coef_s, m_s
//   phase 2b: all 1024 threads: W^T[j][i] = sum_h coef*exp(s-m) -> global
// ---------------------------------------------------------------------------
__global__ __launch_bounds__(1024) void k2_attn(
    const float* __restrict__ w1, const float* __restrict__ b1,
    const float* __restrict__ wqkv, const float* __restrict__ wproj,
    const float* __restrict__ bproj, const float* __restrict__ w2,
    const float* __restrict__ b2, float* __restrict__ ws)
{
    __shared__ float arow[96], crow[96], pvec[32];
    __shared__ float cst[16];
    __shared__ float G_s[64 * 65];
    __shared__ float sxp_s[16][64];
    __shared__ float sx_s[64];
    __shared__ float coef_s[4][64];
    __shared__ float m_s[4][64];
    int b = blockIdx.x, t = threadIdx.x;

    // phase 0a: per-output-row contractions of wqkv with w1/b1, w2.wproj
    if (t < 96) {
        float sa = 0.f, sc = 0.f;
        for (int c = 0; c < 32; ++c) {
            float w = wqkv[t * 32 + c];
            sa += w * w1[c];
            sc += w * b1[c];
        }
        arow[t] = sa; crow[t] = sc;
    } else if (t < 128) {
        int c = t - 96;
        float s = 0.f;
        for (int oc = 0; oc < 32; ++oc) s += w2[oc] * wproj[oc * 32 + c];
        pvec[c] = s;
    }

    // phase 1a: reduce 16 partial Grams (coalesced, 4 acc chains)
    {
        const float* p0 = ws + PART_OFF + (size_t)(b * 16) * 4096 + t;
        float a0 = 0.f, a1 = 0.f, a2 = 0.f, a3 = 0.f;
        #pragma unroll
        for (int r = 0; r < 16; ++r) {
            const float* pr = p0 + (size_t)r * 4096;
            a0 += pr[0]; a1 += pr[1024]; a2 += pr[2048]; a3 += pr[3072];
        }
        int e0 = t;
        G_s[(e0 >> 6) * 65 + (e0 & 63)] = a0;
        int e1 = t + 1024;
        G_s[(e1 >> 6) * 65 + (e1 & 63)] = a1;
        int e2 = t + 2048;
        G_s[(e2 >> 6) * 65 + (e2 & 63)] = a2;
        int e3 = t + 3072;
        G_s[(e3 >> 6) * 65 + (e3 & 63)] = a3;
    }

    // phase 1b: reduce partial token sums (16 x 64 -> 64)
    {
        int j = t & 63, rg = t >> 6;     // rg in [0,16)
        sxp_s[rg][j] = ws[SXP_OFF + (b * 16 + rg) * 64 + j];
    }
    __syncthreads();
    if (t < 64) {
        float s = 0.f;
        #pragma unroll
        for (int r = 0; r < 16; ++r) s += sxp_s[r][t];
        sx_s[t] = s;
    }

    // phase 0b: combine into the 13 scalars
    const float scale = 1.0f / (4096.0f * 2.8284271247461903f); // 1/(P*sqrt(d))
    if (t >= 64 && t < 68) {
        int h = t - 64;
        float A = 0.f, Bk = 0.f, g = 0.f;
        #pragma unroll
        for (int dd = 0; dd < 8; ++dd) {
            int o = h * 8 + dd;
            A  += arow[o] * arow[32 + o];   // aq . ak
            Bk += crow[o] * arow[32 + o];   // cq . ak
            g  += pvec[o] * arow[64 + o];   // pvec . av
        }
        cst[h]     = A * scale;
        cst[4 + h] = Bk * scale;
        cst[8 + h] = g;
    } else if (t == 68) {
        float c0 = b2[0];
        for (int c = 0; c < 32; ++c)  c0 += pvec[c] * crow[64 + c];
        for (int oc = 0; oc < 32; ++oc) c0 += w2[oc] * bproj[oc];
        cst[12] = c0;
    }
    __syncthreads();

    // phase 2a: per (head, row): running max and Z, recomputing s from LDS
    if (t < 256) {
        int h = t >> 6, i = t & 63;
        float A  = cst[h];
        float Bk = cst[4 + h];
        float g  = cst[8 + h];
        float m = -1e30f;
        for (int j = 0; j < 64; ++j) {
            float s = A * G_s[i * 65 + j] + Bk * sx_s[j];
            m = fmaxf(m, s);
        }
        float Z = 0.f;
        for (int j = 0; j < 64; ++j) {
            float s = A * G_s[i * 65 + j] + Bk * sx_s[j];
            Z += __expf(s - m);
        }
        coef_s[h][i] = g / Z;
        m_s[h][i]    = m;
    }
    __syncthreads();

    // phase 2b: every thread writes 4 entries of W^T (coalesced on global)
    {
        float A0 = cst[0], A1 = cst[1], A2 = cst[2], A3 = cst[3];
        float B0 = cst[4], B1 = cst[5], B2 = cst[6], B3 = cst[7];
        #pragma unroll
        for (int k = 0; k < 4; ++k) {
            int e = t + 1024 * k;         // flat index j*64+i
            int j = e >> 6, i = e & 63;
            float G  = G_s[i * 65 + j];
            float sx = sx_s[j];
            float w =
                coef_s[0][i] * __expf(A0 * G + B0 * sx - m_s[0][i]) +
                coef_s[1][i] * __expf(A1 * G + B1 * sx - m_s[1][i]) +
                coef_s[2][i] * __expf(A2 * G + B2 * sx - m_s[2][i]) +
                coef_s[3][i] * __expf(A3 * G + B3 * sx - m_s[3][i]);
            ws[WT_OFF + b * 4096 + e] = w;
        }
    }
    if (b == 0 && t == 0) ws[CONST_OFF + 12] = cst[12];
}

// ---------------------------------------------------------------------------
// K3: out[b, ti*64+pr, tk*64+c] = const0 + sum_j W[b, 8ti+tk, j] * X_j(pr,c)
// 512 blocks x 256 threads; same LDS tiling as original k1 + staged W^T.
// ---------------------------------------------------------------------------
__global__ __launch_bounds__(256) void k3_apply(const float* __restrict__ x,
                                                const float* __restrict__ ws,
                                                float* __restrict__ out)
{
    __shared__ float xs[64 * 68];
    __shared__ float Wt_s[64 * 68];
    int b = blockIdx.x >> 6, pr = blockIdx.x & 63;
    int t = threadIdx.x;
    const float* xb = x + (size_t)b * 262144;
    #pragma unroll
    for (int k = 0; k < 4; ++k) {
        int q = t + 256 * k;
        int tj = q >> 7, col4 = q & 127;
        float4 v = *(const float4*)(xb + (tj * 64 + pr) * 512 + col4 * 4);
        int token = tj * 8 + (col4 >> 4);
        *(float4*)(&xs[token * 68 + (col4 & 15) * 4]) = v;
        // stage W^T: ws[WT_OFF + b*4096 + j*64 + i] -> Wt_s[j][i]
        int j = q >> 4, i0 = (q & 15) * 4;
        float4 wv = *(const float4*)(ws + WT_OFF + b * 4096 + q * 4);
        *(float4*)(&Wt_s[j * 68 + i0]) = wv;
    }
    __syncthreads();

    int tcx = t & 15, tiy = t >> 4;
    float acc[4][4];                       // [u = i offset][v = c offset]
    #pragma unroll
    for (int u = 0; u < 4; ++u)
        #pragma unroll
        for (int v = 0; v < 4; ++v) acc[u][v] = 0.f;

    #pragma unroll 8
    for (int j = 0; j < 64; ++j) {
        float4 wv = *(const float4*)(&Wt_s[j * 68 + 4 * tiy]); // 4 rows i
        float4 xv = *(const float4*)(&xs[j * 68 + 4 * tcx]);   // 4 cols c
        acc[0][0] += wv.x * xv.x; acc[0][1] += wv.x * xv.y;
        acc[0][2] += wv.x * xv.z; acc[0][3] += wv.x * xv.w;
        acc[1][0] += wv.y * xv.x; acc[1][1] += wv.y * xv.y;
        acc[1][2] += wv.y * xv.z; acc[1][3] += wv.y * xv.w;
        acc[2][0] += wv.z * xv.x; acc[2][1] += wv.z * xv.y;
        acc[2][2] += wv.z * xv.z; acc[2][3] += wv.z * xv.w;
        acc[3][0] += wv.w * xv.x; acc[3][1] += wv.w * xv.y;
        acc[3][2] += wv.w * xv.z; acc[3][3] += wv.w * xv.w;
    }

    float c0 = ws[CONST_OFF + 12];
    float* ob = out + (size_t)b * 262144;
    #pragma unroll
    for (int u = 0; u < 4; ++u) {
        int i = 4 * tiy + u;
        int ti = i >> 3, tk = i & 7;
        float4 r;
        r.x = acc[u][0] + c0; r.y = acc[u][1] + c0;
        r.z = acc[u][2] + c0; r.w = acc[u][3] + c0;
        *(float4*)(ob + (ti * 64 + pr) * 512 + tk * 64 + 4 * tcx) = r;
    }
}

extern "C" void kernel_launch(void* const* d_in, const int* in_sizes, int n_in,
                              void* d_out, int out_size, void* d_ws, size_t ws_size,
                              hipStream_t stream) {
    const float* x     = (const float*)d_in[0];
    // d_in[1] = n, d_in[2] = m  (fixed 8 by setup_inputs)
    const float* w1    = (const float*)d_in[3];
    const float* b1    = (const float*)d_in[4];
    const float* wqkv  = (const float*)d_in[5];
    const float* wproj = (const float*)d_in[6];
    const float* bproj = (const float*)d_in[7];
    const float* w2    = (const float*)d_in[8];
    const float* b2    = (const float*)d_in[9];
    float* out = (float*)d_out;
    float* ws  = (float*)d_ws;

    k1_gram<<<128, 256, 0, stream>>>(x, ws);
    k2_attn<<<8, 1024, 0, stream>>>(w1, b1, wqkv, wproj, bproj, w2, b2, ws);
    k3_apply<<<512, 256, 0, stream>>>(x, ws, out);
}

// Round 6
// 90.670 us; speedup vs baseline: 1.5629x; 1.0404x over previous
//
#include <hip/hip_runtime.h>

// ---------------------------------------------------------------------------
// Algebraic collapse of the whole model:
//   X[b, s, p]  = x[b, 0, ti*64+pr, tk*64+pc],  s = 8*ti+tk, p = 64*pr+pc
//   scores[b,h,i,j] ~ A'_h * G[b,i,j] + Bk'_h * sX[b,j]   (+ j-const terms
//                     that cancel in softmax);  G = token Gram of raw X
//   out[b,i,p] = sum_j W[b,i,j] * X[b,j,p] + const0,
//   W[b,i,j]   = sum_h g_h * softmax_j(scores)_h
//
// R5 lesson: k1-MFMA paid ~2x its naive estimate (graph serialization).
// R6: k3 also via MFMA — stage X^T (bf16, LDS transpose) + W[i][j] bf16,
// contraction over tokens j with the SAME verified mfma pattern as k1.
// k2 now emits W row-major [i][j] (was transposed).
// ---------------------------------------------------------------------------

#define CONST_OFF 0                       // 16 floats: c0 at [12]
#define SXP_OFF   16                      // 128*64 partial token sums
#define W_OFF     (16 + 128*64)           // W row-major: [b][i][j], 8*4096
#define PART_OFF  (W_OFF + 8*4096)        // partial Grams: [128 blocks][4096]

typedef __attribute__((ext_vector_type(8))) short bf16x8;
typedef __attribute__((ext_vector_type(4))) float f32x4;

__device__ __forceinline__ unsigned short f2bf(float f) {
    unsigned int u = __float_as_uint(f);
    u = (u + 0x7FFFu + ((u >> 16) & 1u)) >> 16;   // RNE
    return (unsigned short)u;
}

// ---------------------------------------------------------------------------
// K1: partial Gram via MFMA. 128 blocks (8 b x 16 prg) x 256 threads.
// Stage x as bf16 into xsb[token][k], row stride 272 bf16 (2-way bank
// aliasing = free). 4 waves x 4 j-tiles x 8 K-steps of mfma_16x16x32_bf16.
// ---------------------------------------------------------------------------
__global__ __launch_bounds__(256) void k1_gram(const float* __restrict__ x,
                                               float* __restrict__ ws)
{
    __shared__ unsigned short xsb[64 * 272];
    int b = blockIdx.x >> 4, prg = blockIdx.x & 15;
    int t = threadIdx.x;
    const float* xb = x + (size_t)b * 262144;

    #pragma unroll
    for (int prl = 0; prl < 4; ++prl) {
        int pr = prg * 4 + prl;
        #pragma unroll
        for (int k = 0; k < 4; ++k) {
            int q = t + 256 * k;          // float4 index within 8x512 rows
            int tj = q >> 7, col4 = q & 127;
            float4 v = *(const float4*)(xb + (tj * 64 + pr) * 512 + col4 * 4);
            int token = tj * 8 + (col4 >> 4);
            ushort4 h;
            h.x = f2bf(v.x); h.y = f2bf(v.y); h.z = f2bf(v.z); h.w = f2bf(v.w);
            *(ushort4*)(&xsb[token * 272 + prl * 64 + (col4 & 15) * 4]) = h;
        }
    }
    __syncthreads();

    // token-sum contribution of this K-chunk (from bf16 values; err ~1e-7)
    if (t < 64) {
        const uint4* p = (const uint4*)(&xsb[t * 272]);
        float s = 0.f;
        #pragma unroll
        for (int c = 0; c < 32; ++c) {    // 32 x 8 bf16 = 256 values
            uint4 u = p[c];
            s += __uint_as_float(u.x << 16) + __uint_as_float(u.x & 0xFFFF0000u)
               + __uint_as_float(u.y << 16) + __uint_as_float(u.y & 0xFFFF0000u)
               + __uint_as_float(u.z << 16) + __uint_as_float(u.z & 0xFFFF0000u)
               + __uint_as_float(u.w << 16) + __uint_as_float(u.w & 0xFFFF0000u);
        }
        ws[SXP_OFF + blockIdx.x * 64 + t] = s;
    }

    int w = t >> 6, lane = t & 63;
    int m = lane & 15, quad = lane >> 4;
    f32x4 acc[4];
    #pragma unroll
    for (int jq = 0; jq < 4; ++jq) acc[jq] = (f32x4){0.f, 0.f, 0.f, 0.f};

    #pragma unroll
    for (int s = 0; s < 8; ++s) {
        int kb = s * 32 + quad * 8;
        bf16x8 a = *(const bf16x8*)(&xsb[(w * 16 + m) * 272 + kb]);
        #pragma unroll
        for (int jq = 0; jq < 4; ++jq) {
            bf16x8 bb = *(const bf16x8*)(&xsb[(jq * 16 + m) * 272 + kb]);
            acc[jq] = __builtin_amdgcn_mfma_f32_16x16x32_bf16(a, bb, acc[jq],
                                                              0, 0, 0);
        }
    }

    // C/D layout (m89): col = lane&15 (j), row = (lane>>4)*4 + reg (i)
    float* part = ws + PART_OFF + (size_t)blockIdx.x * 4096;
    #pragma unroll
    for (int jq = 0; jq < 4; ++jq)
        #pragma unroll
        for (int r = 0; r < 4; ++r)
            part[(w * 16 + quad * 4 + r) * 64 + jq * 16 + m] = acc[jq][r];
}

// ---------------------------------------------------------------------------
// K2: per batch (8 blocks x 1024 threads):
//   phase 0: contract weights -> 13 scalars (redundant per block, trivial)
//   phase 1: reduce 16 partial Grams -> G_s (LDS), reduce token sums
//   phase 2a: per (head,row): m and Z via LDS recompute -> coef_s, m_s
//   phase 2b: all threads: W[i][j] = sum_h coef*exp(s-m) -> global (row-major)
// ---------------------------------------------------------------------------
__global__ __launch_bounds__(1024) void k2_attn(
    const float* __restrict__ w1, const float* __restrict__ b1,
    const float* __restrict__ wqkv, const float* __restrict__ wproj,
    const float* __restrict__ bproj, const float* __restrict__ w2,
    const float* __restrict__ b2, float* __restrict__ ws)
{
    __shared__ float arow[96], crow[96], pvec[32];
    __shared__ float cst[16];
    __shared__ float G_s[64 * 65];
    __shared__ float sxp_s[16][64];
    __shared__ float sx_s[64];
    __shared__ float coef_s[4][64];
    __shared__ float m_s[4][64];
    int b = blockIdx.x, t = threadIdx.x;

    // phase 0a: per-output-row contractions of wqkv with w1/b1, w2.wproj
    if (t < 96) {
        float sa = 0.f, sc = 0.f;
        for (int c = 0; c < 32; ++c) {
            float w = wqkv[t * 32 + c];
            sa += w * w1[c];
            sc += w * b1[c];
        }
        arow[t] = sa; crow[t] = sc;
    } else if (t < 128) {
        int c = t - 96;
        float s = 0.f;
        for (int oc = 0; oc < 32; ++oc) s += w2[oc] * wproj[oc * 32 + c];
        pvec[c] = s;
    }

    // phase 1a: reduce 16 partial Grams (coalesced, 4 acc chains)
    {
        const float* p0 = ws + PART_OFF + (size_t)(b * 16) * 4096 + t;
        float a0 = 0.f, a1 = 0.f, a2 = 0.f, a3 = 0.f;
        #pragma unroll
        for (int r = 0; r < 16; ++r) {
            const float* pr = p0 + (size_t)r * 4096;
            a0 += pr[0]; a1 += pr[1024]; a2 += pr[2048]; a3 += pr[3072];
        }
        int e0 = t;
        G_s[(e0 >> 6) * 65 + (e0 & 63)] = a0;
        int e1 = t + 1024;
        G_s[(e1 >> 6) * 65 + (e1 & 63)] = a1;
        int e2 = t + 2048;
        G_s[(e2 >> 6) * 65 + (e2 & 63)] = a2;
        int e3 = t + 3072;
        G_s[(e3 >> 6) * 65 + (e3 & 63)] = a3;
    }

    // phase 1b: reduce partial token sums (16 x 64 -> 64)
    {
        int j = t & 63, rg = t >> 6;     // rg in [0,16)
        sxp_s[rg][j] = ws[SXP_OFF + (b * 16 + rg) * 64 + j];
    }
    __syncthreads();
    if (t < 64) {
        float s = 0.f;
        #pragma unroll
        for (int r = 0; r < 16; ++r) s += sxp_s[r][t];
        sx_s[t] = s;
    }

    // phase 0b: combine into the 13 scalars
    const float scale = 1.0f / (4096.0f * 2.8284271247461903f); // 1/(P*sqrt(d))
    if (t >= 64 && t < 68) {
        int h = t - 64;
        float A = 0.f, Bk = 0.f, g = 0.f;
        #pragma unroll
        for (int dd = 0; dd < 8; ++dd) {
            int o = h * 8 + dd;
            A  += arow[o] * arow[32 + o];   // aq . ak
            Bk += crow[o] * arow[32 + o];   // cq . ak
            g  += pvec[o] * arow[64 + o];   // pvec . av
        }
        cst[h]     = A * scale;
        cst[4 + h] = Bk * scale;
        cst[8 + h] = g;
    } else if (t == 68) {
        float c0 = b2[0];
        for (int c = 0; c < 32; ++c)  c0 += pvec[c] * crow[64 + c];
        for (int oc = 0; oc < 32; ++oc) c0 += w2[oc] * bproj[oc];
        cst[12] = c0;
    }
    __syncthreads();

    // phase 2a: per (head, row): running max and Z, recomputing s from LDS
    if (t < 256) {
        int h = t >> 6, i = t & 63;
        float A  = cst[h];
        float Bk = cst[4 + h];
        float g  = cst[8 + h];
        float m = -1e30f;
        for (int j = 0; j < 64; ++j) {
            float s = A * G_s[i * 65 + j] + Bk * sx_s[j];
            m = fmaxf(m, s);
        }
        float Z = 0.f;
        for (int j = 0; j < 64; ++j) {
            float s = A * G_s[i * 65 + j] + Bk * sx_s[j];
            Z += __expf(s - m);
        }
        coef_s[h][i] = g / Z;
        m_s[h][i]    = m;
    }
    __syncthreads();

    // phase 2b: every thread writes 4 entries of W[i][j] (coalesced)
    {
        float A0 = cst[0], A1 = cst[1], A2 = cst[2], A3 = cst[3];
        float B0 = cst[4], B1 = cst[5], B2 = cst[6], B3 = cst[7];
        #pragma unroll
        for (int k = 0; k < 4; ++k) {
            int e = t + 1024 * k;         // flat index i*64+j (row-major)
            int i = e >> 6, j = e & 63;
            float G  = G_s[i * 65 + j];
            float sx = sx_s[j];
            float w =
                coef_s[0][i] * __expf(A0 * G + B0 * sx - m_s[0][i]) +
                coef_s[1][i] * __expf(A1 * G + B1 * sx - m_s[1][i]) +
                coef_s[2][i] * __expf(A2 * G + B2 * sx - m_s[2][i]) +
                coef_s[3][i] * __expf(A3 * G + B3 * sx - m_s[3][i]);
            ws[W_OFF + b * 4096 + e] = w;
        }
    }
    if (b == 0 && t == 0) ws[CONST_OFF + 12] = cst[12];
}

// ---------------------------------------------------------------------------
// K3: out[b, i, pr, c] = const0 + sum_j W[b,i,j] * X[b,j,(pr,c)] via MFMA.
// 512 blocks (b x pr) x 256 threads. Stage X^T[c][j] bf16 (LDS transpose,
// stride 72: frag reads 2-way = free; scatter b16 writes ~8-way, acceptable)
// and W[i][j] bf16 (stride 72). K=64 -> 2 MFMA k-steps. Same frag/output
// mapping as k1 (A row -> D row, B row -> D col).
// ---------------------------------------------------------------------------
__global__ __launch_bounds__(256) void k3_apply(const float* __restrict__ x,
                                                const float* __restrict__ ws,
                                                float* __restrict__ out)
{
    __shared__ unsigned short xt[64 * 72];   // [c][j]
    __shared__ unsigned short wsm[64 * 72];  // [i][j]
    int b = blockIdx.x >> 6, pr = blockIdx.x & 63;
    int t = threadIdx.x;
    const float* xb = x + (size_t)b * 262144;

    #pragma unroll
    for (int k = 0; k < 4; ++k) {
        int q = t + 256 * k;              // float4 idx in [0,1024)
        int j = q >> 4, c4 = q & 15;      // token j, float4-within-row c4
        int ti = j >> 3, tk = j & 7;
        float4 v = *(const float4*)(xb + (ti * 64 + pr) * 512 + tk * 64 + c4 * 4);
        xt[(4 * c4 + 0) * 72 + j] = f2bf(v.x);
        xt[(4 * c4 + 1) * 72 + j] = f2bf(v.y);
        xt[(4 * c4 + 2) * 72 + j] = f2bf(v.z);
        xt[(4 * c4 + 3) * 72 + j] = f2bf(v.w);
        // W: same q covers 1024 float4 = 4096 floats
        int i = q >> 4, j4 = q & 15;
        float4 wv = *(const float4*)(ws + W_OFF + b * 4096 + q * 4);
        ushort4 h;
        h.x = f2bf(wv.x); h.y = f2bf(wv.y); h.z = f2bf(wv.z); h.w = f2bf(wv.w);
        *(ushort4*)(&wsm[i * 72 + j4 * 4]) = h;
    }
    __syncthreads();

    int w = t >> 6, lane = t & 63;
    int m = lane & 15, quad = lane >> 4;
    f32x4 acc[4];
    #pragma unroll
    for (int jq = 0; jq < 4; ++jq) acc[jq] = (f32x4){0.f, 0.f, 0.f, 0.f};

    #pragma unroll
    for (int s = 0; s < 2; ++s) {
        int kb = s * 32 + quad * 8;
        bf16x8 a = *(const bf16x8*)(&wsm[(w * 16 + m) * 72 + kb]);   // W[i][k]
        #pragma unroll
        for (int jq = 0; jq < 4; ++jq) {
            bf16x8 bv = *(const bf16x8*)(&xt[(jq * 16 + m) * 72 + kb]); // X^T[c][k]
            acc[jq] = __builtin_amdgcn_mfma_f32_16x16x32_bf16(a, bv, acc[jq],
                                                              0, 0, 0);
        }
    }

    float c0 = ws[CONST_OFF + 12];
    float* ob = out + (size_t)b * 262144;
    // D row = i (A's row), D col = c (B's row): col=lane&15, row=quad*4+r
    #pragma unroll
    for (int jq = 0; jq < 4; ++jq)
        #pragma unroll
        for (int r = 0; r < 4; ++r) {
            int i = w * 16 + quad * 4 + r;
            int c = jq * 16 + m;
            int ti = i >> 3, tk = i & 7;
            ob[(ti * 64 + pr) * 512 + tk * 64 + c] = acc[jq][r] + c0;
        }
}

extern "C" void kernel_launch(void* const* d_in, const int* in_sizes, int n_in,
                              void* d_out, int out_size, void* d_ws, size_t ws_size,
                              hipStream_t stream) {
    const float* x     = (const float*)d_in[0];
    // d_in[1] = n, d_in[2] = m  (fixed 8 by setup_inputs)
    const float* w1    = (const float*)d_in[3];
    const float* b1    = (const float*)d_in[4];
    const float* wqkv  = (const float*)d_in[5];
    const float* wproj = (const float*)d_in[6];
    const float* bproj = (const float*)d_in[7];
    const float* w2    = (const float*)d_in[8];
    const float* b2    = (const float*)d_in[9];
    float* out = (float*)d_out;
    float* ws  = (float*)d_ws;

    k1_gram<<<128, 256, 0, stream>>>(x, ws);
    k2_attn<<<8, 1024, 0, stream>>>(w1, b1, wqkv, wproj, bproj, w2, b2, ws);
    k3_apply<<<512, 256, 0, stream>>>(x, ws, out);
}

// Round 8
// 89.717 us; speedup vs baseline: 1.5795x; 1.0106x over previous
//
#include <hip/hip_runtime.h>

// ---------------------------------------------------------------------------
// Algebraic collapse of the whole model:
//   X[b, s, p]  = x[b, 0, ti*64+pr, tk*64+pc],  s = 8*ti+tk, p = 64*pr+pc
//   scores[b,h,i,j] ~ A'_h * G[b,i,j] + Bk'_h * sX[b,j]   (+ j-const terms
//                     that cancel in softmax);  G = token Gram of raw X
//   out[b,i,p] = sum_j W[b,i,j] * X[b,j,p] + const0,
//   W[b,i,j]   = sum_h g_h * softmax_j(scores)_h
//
// R7 lesson: W went fp32->bf16 but k3's staging loop still copied only half
// the matrix (2048 of 4096 ushorts) -> uninitialized LDS -> NaN. R8: copy W
// with uint4 (8 ushorts/op, 512 ops = full matrix). No other changes.
// ---------------------------------------------------------------------------

#define CONST_OFF 0                       // 16 floats: c0 at [12]
#define SXP_OFF   16                      // 128*64 partial token sums
#define WB_OFF    (16 + 128*64)           // W bf16 [b][i][j]: 8*4096 ushort = 16384 floats
#define PART_OFF  (WB_OFF + 8*2048)       // partial Grams: [128 blocks][4096] fp32

typedef __attribute__((ext_vector_type(8))) short bf16x8;
typedef __attribute__((ext_vector_type(4))) float f32x4;

__device__ __forceinline__ unsigned short f2bf(float f) {
    unsigned int u = __float_as_uint(f);
    u = (u + 0x7FFFu + ((u >> 16) & 1u)) >> 16;   // RNE
    return (unsigned short)u;
}

// ---------------------------------------------------------------------------
// K1: partial Gram via MFMA. 128 blocks (8 b x 16 prg) x 256 threads.
// Stage x as bf16 into xsb[token][k], row stride 272 bf16 (2-way bank
// aliasing = free). 4 waves x 4 j-tiles x 8 K-steps of mfma_16x16x32_bf16.
// ---------------------------------------------------------------------------
__global__ __launch_bounds__(256) void k1_gram(const float* __restrict__ x,
                                               float* __restrict__ ws)
{
    __shared__ unsigned short xsb[64 * 272];
    int b = blockIdx.x >> 4, prg = blockIdx.x & 15;
    int t = threadIdx.x;
    const float* xb = x + (size_t)b * 262144;

    #pragma unroll
    for (int prl = 0; prl < 4; ++prl) {
        int pr = prg * 4 + prl;
        #pragma unroll
        for (int k = 0; k < 4; ++k) {
            int q = t + 256 * k;          // float4 index within 8x512 rows
            int tj = q >> 7, col4 = q & 127;
            float4 v = *(const float4*)(xb + (tj * 64 + pr) * 512 + col4 * 4);
            int token = tj * 8 + (col4 >> 4);
            ushort4 h;
            h.x = f2bf(v.x); h.y = f2bf(v.y); h.z = f2bf(v.z); h.w = f2bf(v.w);
            *(ushort4*)(&xsb[token * 272 + prl * 64 + (col4 & 15) * 4]) = h;
        }
    }
    __syncthreads();

    // token-sum contribution of this K-chunk (from bf16 values; err ~1e-7)
    if (t < 64) {
        const uint4* p = (const uint4*)(&xsb[t * 272]);
        float s = 0.f;
        #pragma unroll
        for (int c = 0; c < 32; ++c) {    // 32 x 8 bf16 = 256 values
            uint4 u = p[c];
            s += __uint_as_float(u.x << 16) + __uint_as_float(u.x & 0xFFFF0000u)
               + __uint_as_float(u.y << 16) + __uint_as_float(u.y & 0xFFFF0000u)
               + __uint_as_float(u.z << 16) + __uint_as_float(u.z & 0xFFFF0000u)
               + __uint_as_float(u.w << 16) + __uint_as_float(u.w & 0xFFFF0000u);
        }
        ws[SXP_OFF + blockIdx.x * 64 + t] = s;
    }

    int w = t >> 6, lane = t & 63;
    int m = lane & 15, quad = lane >> 4;
    f32x4 acc[4];
    #pragma unroll
    for (int jq = 0; jq < 4; ++jq) acc[jq] = (f32x4){0.f, 0.f, 0.f, 0.f};

    #pragma unroll
    for (int s = 0; s < 8; ++s) {
        int kb = s * 32 + quad * 8;
        bf16x8 a = *(const bf16x8*)(&xsb[(w * 16 + m) * 272 + kb]);
        #pragma unroll
        for (int jq = 0; jq < 4; ++jq) {
            bf16x8 bb = *(const bf16x8*)(&xsb[(jq * 16 + m) * 272 + kb]);
            acc[jq] = __builtin_amdgcn_mfma_f32_16x16x32_bf16(a, bb, acc[jq],
                                                              0, 0, 0);
        }
    }

    // C/D layout (m89): col = lane&15 (j), row = (lane>>4)*4 + reg (i)
    float* part = ws + PART_OFF + (size_t)blockIdx.x * 4096;
    #pragma unroll
    for (int jq = 0; jq < 4; ++jq)
        #pragma unroll
        for (int r = 0; r < 4; ++r)
            part[(w * 16 + quad * 4 + r) * 64 + jq * 16 + m] = acc[jq][r];
}

// ---------------------------------------------------------------------------
// K2: 64 blocks (b x row-group rg of 8 rows) x 256 threads:
//   phase 0: contract weights -> 13 scalars (redundant per block, trivial)
//   phase 1: reduce this block's 8 G-rows (16 partials x 512 floats) + sx
//   phase 2a: softmax (m, Z) for 32 (head,row) pairs
//   phase 2b: W[i][j] -> global as bf16 (k3 stages it raw)
// ---------------------------------------------------------------------------
__global__ __launch_bounds__(256) void k2_attn(
    const float* __restrict__ w1, const float* __restrict__ b1,
    const float* __restrict__ wqkv, const float* __restrict__ wproj,
    const float* __restrict__ bproj, const float* __restrict__ w2,
    const float* __restrict__ b2, float* __restrict__ ws)
{
    __shared__ float arow[96], crow[96], pvec[32];
    __shared__ float cst[16];
    __shared__ float G_s[8 * 65];        // 8 local rows, pad 65
    __shared__ float sxp_s[4][64];
    __shared__ float sx_s[64];
    __shared__ float coef_s[4][8];
    __shared__ float m_s[4][8];
    int b = blockIdx.x >> 3, rg = blockIdx.x & 7;
    int t = threadIdx.x;

    // phase 0a: per-output-row contractions of wqkv with w1/b1, w2.wproj
    if (t < 96) {
        float sa = 0.f, sc = 0.f;
        for (int c = 0; c < 32; ++c) {
            float w = wqkv[t * 32 + c];
            sa += w * w1[c];
            sc += w * b1[c];
        }
        arow[t] = sa; crow[t] = sc;
    } else if (t < 128) {
        int c = t - 96;
        float s = 0.f;
        for (int oc = 0; oc < 32; ++oc) s += w2[oc] * wproj[oc * 32 + c];
        pvec[c] = s;
    }

    // phase 1a: reduce this block's 8 G-rows over 16 partials (coalesced)
    {
        const float* p0 = ws + PART_OFF + (size_t)(b * 16) * 4096 + rg * 512;
        float a0 = 0.f, a1 = 0.f;
        #pragma unroll
        for (int r = 0; r < 16; ++r) {
            const float* pr = p0 + (size_t)r * 4096;
            a0 += pr[t]; a1 += pr[t + 256];
        }
        int e0 = t;          G_s[(e0 >> 6) * 65 + (e0 & 63)] = a0;
        int e1 = t + 256;    G_s[(e1 >> 6) * 65 + (e1 & 63)] = a1;
    }

    // phase 1b: reduce partial token sums (16 x 64 -> 64)
    {
        int j = t & 63, r4 = t >> 6;     // r4 in [0,4)
        float s = 0.f;
        #pragma unroll
        for (int k = 0; k < 4; ++k)
            s += ws[SXP_OFF + (b * 16 + r4 * 4 + k) * 64 + j];
        sxp_s[r4][j] = s;
    }
    __syncthreads();
    if (t < 64)
        sx_s[t] = sxp_s[0][t] + sxp_s[1][t] + sxp_s[2][t] + sxp_s[3][t];

    // phase 0b: combine into the 13 scalars
    const float scale = 1.0f / (4096.0f * 2.8284271247461903f); // 1/(P*sqrt(d))
    if (t >= 64 && t < 68) {
        int h = t - 64;
        float A = 0.f, Bk = 0.f, g = 0.f;
        #pragma unroll
        for (int dd = 0; dd < 8; ++dd) {
            int o = h * 8 + dd;
            A  += arow[o] * arow[32 + o];   // aq . ak
            Bk += crow[o] * arow[32 + o];   // cq . ak
            g  += pvec[o] * arow[64 + o];   // pvec . av
        }
        cst[h]     = A * scale;
        cst[4 + h] = Bk * scale;
        cst[8 + h] = g;
    } else if (t == 68) {
        float c0 = b2[0];
        for (int c = 0; c < 32; ++c)  c0 += pvec[c] * crow[64 + c];
        for (int oc = 0; oc < 32; ++oc) c0 += w2[oc] * bproj[oc];
        cst[12] = c0;
    }
    __syncthreads();

    // phase 2a: softmax stats for 32 (head, local-row) pairs
    if (t < 32) {
        int h = t >> 3, il = t & 7;
        float A  = cst[h];
        float Bk = cst[4 + h];
        float g  = cst[8 + h];
        float m = -1e30f;
        for (int j = 0; j < 64; ++j) {
            float s = A * G_s[il * 65 + j] + Bk * sx_s[j];
            m = fmaxf(m, s);
        }
        float Z = 0.f;
        for (int j = 0; j < 64; ++j) {
            float s = A * G_s[il * 65 + j] + Bk * sx_s[j];
            Z += __expf(s - m);
        }
        coef_s[h][il] = g / Z;
        m_s[h][il]    = m;
    }
    __syncthreads();

    // phase 2b: 512 W entries as bf16 (row-major [i][j])
    {
        float A0 = cst[0], A1 = cst[1], A2 = cst[2], A3 = cst[3];
        float B0 = cst[4], B1 = cst[5], B2 = cst[6], B3 = cst[7];
        unsigned short* wout =
            (unsigned short*)(ws + WB_OFF) + b * 4096 + rg * 512;
        #pragma unroll
        for (int k = 0; k < 2; ++k) {
            int e = t + 256 * k;          // local flat index il*64+j
            int il = e >> 6, j = e & 63;
            float G  = G_s[il * 65 + j];
            float sx = sx_s[j];
            float w =
                coef_s[0][il] * __expf(A0 * G + B0 * sx - m_s[0][il]) +
                coef_s[1][il] * __expf(A1 * G + B1 * sx - m_s[1][il]) +
                coef_s[2][il] * __expf(A2 * G + B2 * sx - m_s[2][il]) +
                coef_s[3][il] * __expf(A3 * G + B3 * sx - m_s[3][il]);
            wout[e] = f2bf(w);
        }
    }
    if (b == 0 && rg == 0 && t == 68) ws[CONST_OFF + 12] = cst[12];
}

// ---------------------------------------------------------------------------
// K3: out[b, i, pr, c] = const0 + sum_j W[b,i,j] * X[b,j,(pr,c)] via MFMA.
// 512 blocks (b x pr) x 256 threads. Stage X^T[c][j] bf16 (LDS transpose,
// stride 72) and W[i][j] bf16 via uint4 copy (8 ushorts/op x 512 ops =
// full 4096-ushort matrix — R7's bug was copying only half). K=64 -> 2
// MFMA k-steps.
// ---------------------------------------------------------------------------
__global__ __launch_bounds__(256) void k3_apply(const float* __restrict__ x,
                                                const float* __restrict__ ws,
                                                float* __restrict__ out)
{
    __shared__ unsigned short xt[64 * 72];   // [c][j]
    __shared__ unsigned short wsm[64 * 72];  // [i][j]
    int b = blockIdx.x >> 6, pr = blockIdx.x & 63;
    int t = threadIdx.x;
    const float* xb = x + (size_t)b * 262144;

    #pragma unroll
    for (int k = 0; k < 4; ++k) {
        int q = t + 256 * k;              // float4 idx in [0,1024)
        int j = q >> 4, c4 = q & 15;      // token j, float4-within-row c4
        int ti = j >> 3, tk = j & 7;
        float4 v = *(const float4*)(xb + (ti * 64 + pr) * 512 + tk * 64 + c4 * 4);
        xt[(4 * c4 + 0) * 72 + j] = f2bf(v.x);
        xt[(4 * c4 + 1) * 72 + j] = f2bf(v.y);
        xt[(4 * c4 + 2) * 72 + j] = f2bf(v.z);
        xt[(4 * c4 + 3) * 72 + j] = f2bf(v.w);
    }
    {   // W: 4096 ushort = 512 uint4 (8 ushorts each); q in [0,512)
        const uint4* wb = (const uint4*)((const unsigned short*)(ws + WB_OFF)
                                         + b * 4096);
        #pragma unroll
        for (int k = 0; k < 2; ++k) {
            int q = t + 256 * k;
            int i = q >> 3, j8 = q & 7;   // flat = q*8 = i*64 + j8*8
            *(uint4*)(&wsm[i * 72 + j8 * 8]) = wb[q];
        }
    }
    __syncthreads();

    int w = t >> 6, lane = t & 63;
    int m = lane & 15, quad = lane >> 4;
    f32x4 acc[4];
    #pragma unroll
    for (int jq = 0; jq < 4; ++jq) acc[jq] = (f32x4){0.f, 0.f, 0.f, 0.f};

    #pragma unroll
    for (int s = 0; s < 2; ++s) {
        int kb = s * 32 + quad * 8;
        bf16x8 a = *(const bf16x8*)(&wsm[(w * 16 + m) * 72 + kb]);   // W[i][k]
        #pragma unroll
        for (int jq = 0; jq < 4; ++jq) {
            bf16x8 bv = *(const bf16x8*)(&xt[(jq * 16 + m) * 72 + kb]); // X^T[c][k]
            acc[jq] = __builtin_amdgcn_mfma_f32_16x16x32_bf16(a, bv, acc[jq],
                                                              0, 0, 0);
        }
    }

    float c0 = ws[CONST_OFF + 12];
    float* ob = out + (size_t)b * 262144;
    // D row = i (A's row), D col = c (B's row): col=lane&15, row=quad*4+r
    #pragma unroll
    for (int jq = 0; jq < 4; ++jq)
        #pragma unroll
        for (int r = 0; r < 4; ++r) {
            int i = w * 16 + quad * 4 + r;
            int c = jq * 16 + m;
            int ti = i >> 3, tk = i & 7;
            ob[(ti * 64 + pr) * 512 + tk * 64 + c] = acc[jq][r] + c0;
        }
}

extern "C" void kernel_launch(void* const* d_in, const int* in_sizes, int n_in,
                              void* d_out, int out_size, void* d_ws, size_t ws_size,
                              hipStream_t stream) {
    const float* x     = (const float*)d_in[0];
    // d_in[1] = n, d_in[2] = m  (fixed 8 by setup_inputs)
    const float* w1    = (const float*)d_in[3];
    const float* b1    = (const float*)d_in[4];
    const float* wqkv  = (const float*)d_in[5];
    const float* wproj = (const float*)d_in[6];
    const float* bproj = (const float*)d_in[7];
    const float* w2    = (const float*)d_in[8];
    const float* b2    = (const float*)d_in[9];
    float* out = (float*)d_out;
    float* ws  = (float*)d_ws;

    k1_gram<<<128, 256, 0, stream>>>(x, ws);
    k2_attn<<<64, 256, 0, stream>>>(w1, b1, wqkv, wproj, bproj, w2, b2, ws);
    k3_apply<<<512, 256, 0, stream>>>(x, ws, out);
}